// Round 27
// baseline (75.559 us; speedup 1.0000x reference)
//
#include <hip/hip_runtime.h>
#include <hip/hip_bf16.h>
#include <stdint.h>

typedef float f32x4 __attribute__((ext_vector_type(4)));
typedef __bf16 bf16x8 __attribute__((ext_vector_type(8)));
typedef unsigned short u16;

#define MFMA16(a, b, c) __builtin_amdgcn_mfma_f32_16x16x32_bf16((a), (b), (c), 0, 0, 0)

__device__ __forceinline__ u16 f2bf(float f) {
  union { float f; uint32_t u; } v; v.f = f;
  uint32_t u = v.u;
  return (u16)((u + 0x7fffu + ((u >> 16) & 1u)) >> 16);
}
__device__ __forceinline__ float bf2f(u16 h) {
  union { uint32_t u; float f; } v; v.u = ((uint32_t)h) << 16;
  return v.f;
}

// ---------------- kernel 0: weights -> bf16 transposed [c][k] -----------------
__global__ void prep_weights_kernel(const float* __restrict__ Wq, const float* __restrict__ Wk,
                                    const float* __restrict__ Wv, const float* __restrict__ Wp,
                                    u16* __restrict__ Wt) {
  int w = blockIdx.x;
  const float* W = (w == 0) ? Wq : (w == 1) ? Wk : (w == 2) ? Wv : Wp;
  int t = blockIdx.y * 256 + threadIdx.x;  // 0..16383
  int c = t >> 7, k = t & 127;
  Wt[(w * 128 + c) * 128 + k] = f2bf(W[k * 128 + c]);
}

// ---------------- FUSED kernel v15: fused13 + XCD-bijective swizzle ----------
// fused13 (74.7us champion; fused14's deep out-proj pipeline was null) with
// the last zero-risk lever: 400 % 8 == 0, so bid -> (bid&7)*50 + (bid>>3) is
// a bijective XCD swizzle grouping 50 consecutive n per XCD — all blocks on
// one XCD then share the hot Wt panels through their private L2 (T1 regime:
// neighbor blocks share operand panels). Pure index remap; body = fused13.
__global__ __launch_bounds__(512, 2) void fused15_kernel(
    const u16* __restrict__ Wt, const float* __restrict__ x,
    const int* __restrict__ mask, const float* __restrict__ rel,
    const float* __restrict__ bq, const float* __restrict__ bk,
    const float* __restrict__ bv, const float* __restrict__ bp,
    const float* __restrict__ ln_g, const float* __restrict__ ln_b,
    float* __restrict__ out) {
  __shared__ u16 KX[256][136];        // x (per-wave) -> K               69632 B
  __shared__ u16 V_lds[128][264];     // Wq stage -> V^T [d][t]          67584 B
  __shared__ u16 P_lds[8][32][40];    // per-wave repack slices          20480 B
  __shared__ float rel_lds[511];      //                                  2044 B
  __shared__ float vmean_lds[128];    //                                   512 B -> 160252 B
  const int tid = threadIdx.x;
  const int bid = blockIdx.x;
  const int n = (bid & 7) * 50 + (bid >> 3);   // XCD-bijective (400 % 8 == 0)
  const int bb = n / 100, rr = n - bb * 100;
  const int* mrow = mask + bb * 256;
  if (tid < 511) rel_lds[tid] = rel[tid];
  const int l = tid & 63, wv = tid >> 6, l15 = l & 15, l4 = l >> 4;
  const int tt0 = wv * 32;  // this wave's 32 q-rows

#define LOADW4(buf, ROWB)                                                  \
  do {                                                                     \
    const u16* _wp = Wt + (size_t)((ROWB) + l15) * 128 + l4 * 8;           \
    buf[0] = *(const bf16x8*)(_wp);                                        \
    buf[1] = *(const bf16x8*)(_wp + 32);                                   \
    buf[2] = *(const bf16x8*)(_wp + 64);                                   \
    buf[3] = *(const bf16x8*)(_wp + 96);                                   \
  } while (0)

  {  // cooperative Wq -> LDS (dead V_lds region, [128][136] padded layout)
    int row = tid >> 2, cb = (tid & 3) * 32;
    const u16* src = Wt + (size_t)row * 128 + cb;
    u16* dst = (u16*)V_lds + (size_t)row * 136 + cb;
#pragma unroll
    for (int j = 0; j < 4; ++j)
      *(bf16x8*)(dst + j * 8) = *(const bf16x8*)(src + j * 8);
  }
  {  // WAVE-PRIVATE stage, BATCHED: 16 loads issued together, then cvt+store
    int row = tt0 + (l >> 1), half = (l & 1) * 64;
    const float* src = x + ((size_t)(n * 256 + row)) * 128 + half;
    u16* dst = &KX[row][half];
    float4 xr[16];
#pragma unroll
    for (int j = 0; j < 16; ++j) xr[j] = ((const float4*)src)[j];
#pragma unroll
    for (int j = 0; j < 16; ++j) {
      dst[j * 4 + 0] = f2bf(xr[j].x); dst[j * 4 + 1] = f2bf(xr[j].y);
      dst[j * 4 + 2] = f2bf(xr[j].z); dst[j * 4 + 3] = f2bf(xr[j].w);
    }
  }
  int ttg[2][4], qm[2][4];
#pragma unroll
  for (int g = 0; g < 2; ++g)
#pragma unroll
    for (int rg = 0; rg < 4; ++rg) {
      ttg[g][rg] = tt0 + g * 16 + 4 * l4 + rg;
      qm[g][rg] = mrow[ttg[g][rg]];
    }

  // ---- per-wave reads of OWN x rows (A-frags + packed residual) ----
  bf16x8 af[2][4];
#pragma unroll
  for (int g = 0; g < 2; ++g)
#pragma unroll
    for (int ks = 0; ks < 4; ++ks)
      af[g][ks] = *(const bf16x8*)&KX[tt0 + g * 16 + l15][ks * 32 + l4 * 8];
  uint32_t xres[2][4][4];  // x[ttg[g][rg]][ct*16+l15], ct=2c|2c+1 packed
#pragma unroll
  for (int g = 0; g < 2; ++g)
#pragma unroll
    for (int rg = 0; rg < 4; ++rg) {
      const u16* xr = &KX[tt0 + g * 16 + 4 * l4 + rg][0];
#pragma unroll
      for (int c = 0; c < 4; ++c)
        xres[g][rg][c] = (uint32_t)xr[c * 32 + l15] | ((uint32_t)xr[c * 32 + 16 + l15] << 16);
    }
  __syncthreads();  // barrier A: x + Wq staged by ALL waves

  // K/V W-frag prefetch (own cols) — issued now, flies under the whole Q section
  bf16x8 bA[4], bB[4];
  LOADW4(bA, 128 + wv * 16);  // K W-frags
  LOADW4(bB, 256 + wv * 16);  // V W-frags

  const float scale = 0.088388347648318447f;  // 1/sqrt(128)
  f32x4 t0, t1;  // transient per-ct accumulators
#define MF8(buf)                                                           \
  do {                                                                     \
    t0 = f32x4{0.f, 0.f, 0.f, 0.f}; t1 = f32x4{0.f, 0.f, 0.f, 0.f};       \
    _Pragma("unroll") for (int ks = 0; ks < 4; ++ks) {                     \
      t0 = MFMA16(af[0][ks], buf[ks], t0);                                 \
      t1 = MFMA16(af[1][ks], buf[ks], t1);                                 \
    }                                                                      \
  } while (0)

  // ---- Q = x @ Wq + bq, B-frags from LDS (wq staged in V_lds region) ----
  bf16x8 qa[2][4];
  const u16* wq = (const u16*)V_lds;
#define QSTORE(CT)                                                         \
  do {                                                                     \
    float bqv = bq[(CT) * 16 + l15];                                       \
    _Pragma("unroll") for (int rg = 0; rg < 4; ++rg) {                     \
      P_lds[wv][4 * l4 + rg][((CT) & 1) * 16 + l15] = f2bf((t0[rg] + bqv) * scale); \
      P_lds[wv][16 + 4 * l4 + rg][((CT) & 1) * 16 + l15] = f2bf((t1[rg] + bqv) * scale); \
    }                                                                      \
    if ((CT) & 1) {                                                        \
      qa[0][(CT) >> 1] = *(const bf16x8*)&P_lds[wv][l15][l4 * 8];          \
      qa[1][(CT) >> 1] = *(const bf16x8*)&P_lds[wv][16 + l15][l4 * 8];     \
    }                                                                      \
  } while (0)
#define QSTEP(CT)                                                          \
  do {                                                                     \
    bf16x8 wqf[4];                                                         \
    _Pragma("unroll") for (int ks = 0; ks < 4; ++ks)                       \
      wqf[ks] = *(const bf16x8*)(wq + (size_t)((CT) * 16 + l15) * 136 + ks * 32 + l4 * 8); \
    MF8(wqf);                                                              \
    QSTORE(CT);                                                            \
  } while (0)
  QSTEP(0); QSTEP(1); QSTEP(2); QSTEP(3);
  QSTEP(4); QSTEP(5); QSTEP(6); QSTEP(7);
  __syncthreads();  // barrier Q: all waves done reading wq_lds (balanced work)

  // ---- K & V col-split: wave owns cols [wv*16, wv*16+16); W-frags resident --
  const float bkv = bk[wv * 16 + l15];
  const float bvv = bv[wv * 16 + l15];
  f32x4 kacc[16];
#pragma unroll
  for (int r = 0; r < 16; ++r) {
    bf16x8 xf[4];
#pragma unroll
    for (int ks = 0; ks < 4; ++ks)
      xf[ks] = *(const bf16x8*)&KX[r * 16 + l15][ks * 32 + l4 * 8];
    f32x4 ka = f32x4{0.f, 0.f, 0.f, 0.f};
    f32x4 va = f32x4{0.f, 0.f, 0.f, 0.f};
#pragma unroll
    for (int ks = 0; ks < 4; ++ks) {
      ka = MFMA16(xf[ks], bA[ks], ka);   // K: rows r*16.., cols wv*16..
      va = MFMA16(xf[ks], bB[ks], va);   // V: same rows/cols
    }
    kacc[r] = ka;
#pragma unroll
    for (int rg = 0; rg < 4; ++rg)
      V_lds[wv * 16 + l15][r * 16 + 4 * l4 + rg] = f2bf(va[rg] + bvv);
  }
  __syncthreads();  // barrier B: all x reads complete (V also fully written)
#pragma unroll
  for (int r = 0; r < 16; ++r)
#pragma unroll
    for (int rg = 0; rg < 4; ++rg)
      KX[r * 16 + 4 * l4 + rg][wv * 16 + l15] = f2bf(kacc[r][rg] + bkv);
  __syncthreads();  // barrier C: K complete

  {  // in-block vmean over V^T rows
    int d = tid >> 2, seg = tid & 3;
    const u16* vr = &V_lds[d][seg * 64];
    float s = 0.f;
#pragma unroll
    for (int j = 0; j < 8; ++j) {
      uint4 u = *(const uint4*)(vr + j * 8);
      s += bf2f((u16)(u.x & 0xffff)) + bf2f((u16)(u.x >> 16));
      s += bf2f((u16)(u.y & 0xffff)) + bf2f((u16)(u.y >> 16));
      s += bf2f((u16)(u.z & 0xffff)) + bf2f((u16)(u.z >> 16));
      s += bf2f((u16)(u.w & 0xffff)) + bf2f((u16)(u.w >> 16));
    }
    s += __shfl_xor(s, 1); s += __shfl_xor(s, 2);
    if (seg == 0) vmean_lds[d] = s * (1.f / 256.f);
  }
  float lsum[2][4]; f32x4 cacc[2][8];
#pragma unroll
  for (int g = 0; g < 2; ++g)
#pragma unroll
    for (int rg = 0; rg < 4; ++rg) lsum[g][rg] = 0.f;
#pragma unroll
  for (int g = 0; g < 2; ++g)
#pragma unroll
    for (int ct = 0; ct < 8; ++ct) cacc[g][ct] = f32x4{0.f, 0.f, 0.f, 0.f};
  __syncthreads();  // barrier 3: vmean ready; no more block syncs

  // ---- attention: fixed-max softmax, 32 rows/wave ----
  const int nkv = (wv >> 1) + 1;
  for (int kv = 0; kv < nkv; ++kv) {
    const int s0 = kv * 64;
    f32x4 sacc[2][4];
#pragma unroll
    for (int g = 0; g < 2; ++g)
#pragma unroll
      for (int ct = 0; ct < 4; ++ct) sacc[g][ct] = f32x4{0.f, 0.f, 0.f, 0.f};
#pragma unroll
    for (int ct = 0; ct < 4; ++ct)
#pragma unroll
      for (int ks = 0; ks < 4; ++ks) {
        bf16x8 bfr = *(const bf16x8*)&KX[s0 + ct * 16 + l15][ks * 32 + l4 * 8];
#pragma unroll
        for (int g = 0; g < 2; ++g) sacc[g][ct] = MFMA16(qa[g][ks], bfr, sacc[g][ct]);
      }
    int km[4];
#pragma unroll
    for (int ct = 0; ct < 4; ++ct) km[ct] = mrow[s0 + ct * 16 + l15];
    float p[2][4][4];
#pragma unroll
    for (int g = 0; g < 2; ++g)
#pragma unroll
      for (int ct = 0; ct < 4; ++ct) {
        const int ss = s0 + ct * 16 + l15;
#pragma unroll
        for (int rg = 0; rg < 4; ++rg) {
          float sv = sacc[g][ct][rg] + rel_lds[ttg[g][rg] - ss + 255];
          bool msk = (ss > ttg[g][rg]) | (km[ct] == 0) | (qm[g][rg] == 0);
          sv = msk ? -1.0e9f : sv;
          float pv = __expf(sv);  // masked -> exactly 0
          p[g][ct][rg] = pv;
          lsum[g][rg] += pv;
        }
      }
#pragma unroll
    for (int c = 0; c < 2; ++c) {
#pragma unroll
      for (int g = 0; g < 2; ++g)
#pragma unroll
        for (int c2 = 0; c2 < 2; ++c2)
#pragma unroll
          for (int rg = 0; rg < 4; ++rg)
            P_lds[wv][g * 16 + 4 * l4 + rg][c2 * 16 + l15] = f2bf(p[g][2 * c + c2][rg]);
      bf16x8 pa[2];
#pragma unroll
      for (int g = 0; g < 2; ++g)
        pa[g] = *(const bf16x8*)&P_lds[wv][g * 16 + l15][l4 * 8];
#pragma unroll
      for (int ct = 0; ct < 8; ++ct) {
        bf16x8 vb = *(const bf16x8*)&V_lds[ct * 16 + l15][s0 + c * 32 + l4 * 8];
#pragma unroll
        for (int g = 0; g < 2; ++g) cacc[g][ct] = MFMA16(pa[g], vb, cacc[g][ct]);
      }
    }
  }
  float li[2][4];
#pragma unroll
  for (int g = 0; g < 2; ++g)
#pragma unroll
    for (int rg = 0; rg < 4; ++rg) {
      float rs = lsum[g][rg];
#pragma unroll
      for (int off = 1; off < 16; off <<= 1) rs += __shfl_xor(rs, off);
      li[g][rg] = rs;
    }
  // ---- ctx -> out-proj (ping-pong) -> residual+LN -> scatter ----
  bf16x8 ca[2][4];
#pragma unroll
  for (int q = 0; q < 4; ++q) {
#pragma unroll
    for (int g = 0; g < 2; ++g)
#pragma unroll
      for (int c2 = 0; c2 < 2; ++c2) {
        int ct = 2 * q + c2;
        float vm = vmean_lds[ct * 16 + l15];
#pragma unroll
        for (int rg = 0; rg < 4; ++rg) {
          float cval = cacc[g][ct][rg] / li[g][rg];
          cval = (qm[g][rg] == 0) ? vm : cval;
          P_lds[wv][g * 16 + 4 * l4 + rg][c2 * 16 + l15] = f2bf(cval);
        }
      }
#pragma unroll
    for (int g = 0; g < 2; ++g)
      ca[g][q] = *(const bf16x8*)&P_lds[wv][g * 16 + l15][l4 * 8];
  }
  f32x4 oacc[2][8];
#define OACC(CT)                                                           \
  do {                                                                     \
    oacc[0][CT] = t0; oacc[1][CT] = t1;                                    \
  } while (0)
#define MF8C(buf)                                                          \
  do {                                                                     \
    t0 = f32x4{0.f, 0.f, 0.f, 0.f}; t1 = f32x4{0.f, 0.f, 0.f, 0.f};       \
    _Pragma("unroll") for (int ks = 0; ks < 4; ++ks) {                     \
      t0 = MFMA16(ca[0][ks], buf[ks], t0);                                 \
      t1 = MFMA16(ca[1][ks], buf[ks], t1);                                 \
    }                                                                      \
  } while (0)
  LOADW4(bA, 384 + 0);
  LOADW4(bB, 384 + 16);
  MF8C(bA); LOADW4(bA, 384 + 2 * 16); OACC(0);
  MF8C(bB); LOADW4(bB, 384 + 3 * 16); OACC(1);
  MF8C(bA); LOADW4(bA, 384 + 4 * 16); OACC(2);
  MF8C(bB); LOADW4(bB, 384 + 5 * 16); OACC(3);
  MF8C(bA); LOADW4(bA, 384 + 6 * 16); OACC(4);
  MF8C(bB); LOADW4(bB, 384 + 7 * 16); OACC(5);
  MF8C(bA);                           OACC(6);
  MF8C(bB);                           OACC(7);

  float bpv[8], gv[8], bt[8];
#pragma unroll
  for (int ct = 0; ct < 8; ++ct) {
    int d = ct * 16 + l15;
    bpv[ct] = bp[d]; gv[ct] = ln_g[d]; bt[ct] = ln_b[d];
  }
#pragma unroll
  for (int g = 0; g < 2; ++g)
#pragma unroll
    for (int rg = 0; rg < 4; ++rg) {
      const int tg = ttg[g][rg];
      float yv[8], sum = 0.f, sq = 0.f;
#pragma unroll
      for (int ct = 0; ct < 8; ++ct) {
        uint32_t pr = xres[g][rg][ct >> 1];
        u16 xh = (ct & 1) ? (u16)(pr >> 16) : (u16)(pr & 0xffff);
        float v = oacc[g][ct][rg] + bpv[ct] + bf2f(xh);
        yv[ct] = v; sum += v; sq += v * v;
      }
#pragma unroll
      for (int off = 1; off < 16; off <<= 1) { sum += __shfl_xor(sum, off); sq += __shfl_xor(sq, off); }
      float mean = sum * (1.f / 128.f);
      float var = sq * (1.f / 128.f) - mean * mean;
      float rstd = rsqrtf(var + 1e-5f);
      float* orow = out + (((size_t)(bb * 256 + tg)) * 100 + rr) * 128;
#pragma unroll
      for (int ct = 0; ct < 8; ++ct)
        orow[ct * 16 + l15] = (yv[ct] - mean) * rstd * gv[ct] + bt[ct];
    }
#undef LOADW4
#undef MF8
#undef MF8C
#undef QSTORE
#undef QSTEP
#undef OACC
}

extern "C" void kernel_launch(void* const* d_in, const int* in_sizes, int n_in,
                              void* d_out, int out_size, void* d_ws, size_t ws_size,
                              hipStream_t stream) {
  const float* x    = (const float*)d_in[0];
  const int*   mask = (const int*)d_in[1];
  const float* Wq   = (const float*)d_in[2];
  const float* bq   = (const float*)d_in[3];
  const float* Wk   = (const float*)d_in[4];
  const float* bk   = (const float*)d_in[5];
  const float* Wv   = (const float*)d_in[6];
  const float* bv   = (const float*)d_in[7];
  const float* Wp   = (const float*)d_in[8];
  const float* bp   = (const float*)d_in[9];
  const float* ln_g = (const float*)d_in[10];
  const float* ln_b = (const float*)d_in[11];
  const float* rel  = (const float*)d_in[12];
  float* out = (float*)d_out;
  u16* Wt = (u16*)d_ws;  // [4][128][128] bf16 transposed — only workspace use

  hipLaunchKernelGGL(prep_weights_kernel, dim3(4, 64), dim3(256), 0, stream, Wq, Wk, Wv, Wp, Wt);
  hipLaunchKernelGGL(fused15_kernel, dim3(400), dim3(512), 0, stream,
                     Wt, x, mask, rel, bq, bk, bv, bp, ln_g, ln_b, out);
}

// Round 28
// 74.778 us; speedup vs baseline: 1.0104x; 1.0104x over previous
//
#include <hip/hip_runtime.h>
#include <hip/hip_bf16.h>
#include <stdint.h>

typedef float f32x4 __attribute__((ext_vector_type(4)));
typedef __bf16 bf16x8 __attribute__((ext_vector_type(8)));
typedef unsigned short u16;

#define MFMA16(a, b, c) __builtin_amdgcn_mfma_f32_16x16x32_bf16((a), (b), (c), 0, 0, 0)

__device__ __forceinline__ u16 f2bf(float f) {
  union { float f; uint32_t u; } v; v.f = f;
  uint32_t u = v.u;
  return (u16)((u + 0x7fffu + ((u >> 16) & 1u)) >> 16);
}
__device__ __forceinline__ float bf2f(u16 h) {
  union { uint32_t u; float f; } v; v.u = ((uint32_t)h) << 16;
  return v.f;
}

// ---------------- kernel 0: weights -> bf16 transposed [c][k] -----------------
__global__ void prep_weights_kernel(const float* __restrict__ Wq, const float* __restrict__ Wk,
                                    const float* __restrict__ Wv, const float* __restrict__ Wp,
                                    u16* __restrict__ Wt) {
  int w = blockIdx.x;
  const float* W = (w == 0) ? Wq : (w == 1) ? Wk : (w == 2) ? Wv : Wp;
  int t = blockIdx.y * 256 + threadIdx.x;  // 0..16383
  int c = t >> 7, k = t & 127;
  Wt[(w * 128 + c) * 128 + k] = f2bf(W[k * 128 + c]);
}

// ---------------- FUSED kernel v13 (FINAL, 74.7us total) ---------------------
// Fully-fused per-n block (400 blocks x 512 thr). Mechanisms, each verified by
// within-session A/B: (1) single-kernel fusion (no Q/K/V global round-trip);
// (2) wave-private batched x staging, no pre-barrier; (3) Wq staged ONCE into
// then-dead V_lds -> Q B-frags via ds_read (8x L2 redundancy removed);
// (4) K/V GEMMs column-split with resident W-frags prefetched under Q;
// (5) fixed-max softmax (scores analytically tiny; masked -> exp = 0 exactly),
// row-sums reduced once after the kv loop; (6) causal wave imbalance overlaps
// the out-proj/epilogue (no barrier after attention); (7) ping-pong out-proj
// weight prefetch. Closed by measurement: col-split out-proj (+barrier) x2,
// 16-wave geometry x3 (compiler caps 1024-thr blocks at 64 VGPR), coalesced
// epilogue x2, deeper pipelines, XCD swizzle — all null or negative.
__global__ __launch_bounds__(512, 2) void fused13_kernel(
    const u16* __restrict__ Wt, const float* __restrict__ x,
    const int* __restrict__ mask, const float* __restrict__ rel,
    const float* __restrict__ bq, const float* __restrict__ bk,
    const float* __restrict__ bv, const float* __restrict__ bp,
    const float* __restrict__ ln_g, const float* __restrict__ ln_b,
    float* __restrict__ out) {
  __shared__ u16 KX[256][136];        // x (per-wave) -> K               69632 B
  __shared__ u16 V_lds[128][264];     // Wq stage -> V^T [d][t]          67584 B
  __shared__ u16 P_lds[8][32][40];    // per-wave repack slices          20480 B
  __shared__ float rel_lds[511];      //                                  2044 B
  __shared__ float vmean_lds[128];    //                                   512 B -> 160252 B
  const int tid = threadIdx.x;
  const int n = blockIdx.x;
  const int bb = n / 100, rr = n - bb * 100;
  const int* mrow = mask + bb * 256;
  if (tid < 511) rel_lds[tid] = rel[tid];
  const int l = tid & 63, wv = tid >> 6, l15 = l & 15, l4 = l >> 4;
  const int tt0 = wv * 32;  // this wave's 32 q-rows

#define LOADW4(buf, ROWB)                                                  \
  do {                                                                     \
    const u16* _wp = Wt + (size_t)((ROWB) + l15) * 128 + l4 * 8;           \
    buf[0] = *(const bf16x8*)(_wp);                                        \
    buf[1] = *(const bf16x8*)(_wp + 32);                                   \
    buf[2] = *(const bf16x8*)(_wp + 64);                                   \
    buf[3] = *(const bf16x8*)(_wp + 96);                                   \
  } while (0)

  {  // cooperative Wq -> LDS (dead V_lds region, [128][136] padded layout)
    int row = tid >> 2, cb = (tid & 3) * 32;
    const u16* src = Wt + (size_t)row * 128 + cb;
    u16* dst = (u16*)V_lds + (size_t)row * 136 + cb;
#pragma unroll
    for (int j = 0; j < 4; ++j)
      *(bf16x8*)(dst + j * 8) = *(const bf16x8*)(src + j * 8);
  }
  {  // WAVE-PRIVATE stage, BATCHED: 16 loads issued together, then cvt+store
    int row = tt0 + (l >> 1), half = (l & 1) * 64;
    const float* src = x + ((size_t)(n * 256 + row)) * 128 + half;
    u16* dst = &KX[row][half];
    float4 xr[16];
#pragma unroll
    for (int j = 0; j < 16; ++j) xr[j] = ((const float4*)src)[j];
#pragma unroll
    for (int j = 0; j < 16; ++j) {
      dst[j * 4 + 0] = f2bf(xr[j].x); dst[j * 4 + 1] = f2bf(xr[j].y);
      dst[j * 4 + 2] = f2bf(xr[j].z); dst[j * 4 + 3] = f2bf(xr[j].w);
    }
  }
  int ttg[2][4], qm[2][4];
#pragma unroll
  for (int g = 0; g < 2; ++g)
#pragma unroll
    for (int rg = 0; rg < 4; ++rg) {
      ttg[g][rg] = tt0 + g * 16 + 4 * l4 + rg;
      qm[g][rg] = mrow[ttg[g][rg]];
    }

  // ---- per-wave reads of OWN x rows (A-frags + packed residual) ----
  bf16x8 af[2][4];
#pragma unroll
  for (int g = 0; g < 2; ++g)
#pragma unroll
    for (int ks = 0; ks < 4; ++ks)
      af[g][ks] = *(const bf16x8*)&KX[tt0 + g * 16 + l15][ks * 32 + l4 * 8];
  uint32_t xres[2][4][4];  // x[ttg[g][rg]][ct*16+l15], ct=2c|2c+1 packed
#pragma unroll
  for (int g = 0; g < 2; ++g)
#pragma unroll
    for (int rg = 0; rg < 4; ++rg) {
      const u16* xr = &KX[tt0 + g * 16 + 4 * l4 + rg][0];
#pragma unroll
      for (int c = 0; c < 4; ++c)
        xres[g][rg][c] = (uint32_t)xr[c * 32 + l15] | ((uint32_t)xr[c * 32 + 16 + l15] << 16);
    }
  __syncthreads();  // barrier A: x + Wq staged by ALL waves

  // K/V W-frag prefetch (own cols) — issued now, flies under the whole Q section
  bf16x8 bA[4], bB[4];
  LOADW4(bA, 128 + wv * 16);  // K W-frags
  LOADW4(bB, 256 + wv * 16);  // V W-frags

  const float scale = 0.088388347648318447f;  // 1/sqrt(128)
  f32x4 t0, t1;  // transient per-ct accumulators
#define MF8(buf)                                                           \
  do {                                                                     \
    t0 = f32x4{0.f, 0.f, 0.f, 0.f}; t1 = f32x4{0.f, 0.f, 0.f, 0.f};       \
    _Pragma("unroll") for (int ks = 0; ks < 4; ++ks) {                     \
      t0 = MFMA16(af[0][ks], buf[ks], t0);                                 \
      t1 = MFMA16(af[1][ks], buf[ks], t1);                                 \
    }                                                                      \
  } while (0)

  // ---- Q = x @ Wq + bq, B-frags from LDS (wq staged in V_lds region) ----
  bf16x8 qa[2][4];
  const u16* wq = (const u16*)V_lds;
#define QSTORE(CT)                                                         \
  do {                                                                     \
    float bqv = bq[(CT) * 16 + l15];                                       \
    _Pragma("unroll") for (int rg = 0; rg < 4; ++rg) {                     \
      P_lds[wv][4 * l4 + rg][((CT) & 1) * 16 + l15] = f2bf((t0[rg] + bqv) * scale); \
      P_lds[wv][16 + 4 * l4 + rg][((CT) & 1) * 16 + l15] = f2bf((t1[rg] + bqv) * scale); \
    }                                                                      \
    if ((CT) & 1) {                                                        \
      qa[0][(CT) >> 1] = *(const bf16x8*)&P_lds[wv][l15][l4 * 8];          \
      qa[1][(CT) >> 1] = *(const bf16x8*)&P_lds[wv][16 + l15][l4 * 8];     \
    }                                                                      \
  } while (0)
#define QSTEP(CT)                                                          \
  do {                                                                     \
    bf16x8 wqf[4];                                                         \
    _Pragma("unroll") for (int ks = 0; ks < 4; ++ks)                       \
      wqf[ks] = *(const bf16x8*)(wq + (size_t)((CT) * 16 + l15) * 136 + ks * 32 + l4 * 8); \
    MF8(wqf);                                                              \
    QSTORE(CT);                                                            \
  } while (0)
  QSTEP(0); QSTEP(1); QSTEP(2); QSTEP(3);
  QSTEP(4); QSTEP(5); QSTEP(6); QSTEP(7);
  __syncthreads();  // barrier Q: all waves done reading wq_lds (balanced work)

  // ---- K & V col-split: wave owns cols [wv*16, wv*16+16); W-frags resident --
  const float bkv = bk[wv * 16 + l15];
  const float bvv = bv[wv * 16 + l15];
  f32x4 kacc[16];
#pragma unroll
  for (int r = 0; r < 16; ++r) {
    bf16x8 xf[4];
#pragma unroll
    for (int ks = 0; ks < 4; ++ks)
      xf[ks] = *(const bf16x8*)&KX[r * 16 + l15][ks * 32 + l4 * 8];
    f32x4 ka = f32x4{0.f, 0.f, 0.f, 0.f};
    f32x4 va = f32x4{0.f, 0.f, 0.f, 0.f};
#pragma unroll
    for (int ks = 0; ks < 4; ++ks) {
      ka = MFMA16(xf[ks], bA[ks], ka);   // K: rows r*16.., cols wv*16..
      va = MFMA16(xf[ks], bB[ks], va);   // V: same rows/cols
    }
    kacc[r] = ka;
#pragma unroll
    for (int rg = 0; rg < 4; ++rg)
      V_lds[wv * 16 + l15][r * 16 + 4 * l4 + rg] = f2bf(va[rg] + bvv);
  }
  __syncthreads();  // barrier B: all x reads complete (V also fully written)
#pragma unroll
  for (int r = 0; r < 16; ++r)
#pragma unroll
    for (int rg = 0; rg < 4; ++rg)
      KX[r * 16 + 4 * l4 + rg][wv * 16 + l15] = f2bf(kacc[r][rg] + bkv);
  __syncthreads();  // barrier C: K complete

  {  // in-block vmean over V^T rows
    int d = tid >> 2, seg = tid & 3;
    const u16* vr = &V_lds[d][seg * 64];
    float s = 0.f;
#pragma unroll
    for (int j = 0; j < 8; ++j) {
      uint4 u = *(const uint4*)(vr + j * 8);
      s += bf2f((u16)(u.x & 0xffff)) + bf2f((u16)(u.x >> 16));
      s += bf2f((u16)(u.y & 0xffff)) + bf2f((u16)(u.y >> 16));
      s += bf2f((u16)(u.z & 0xffff)) + bf2f((u16)(u.z >> 16));
      s += bf2f((u16)(u.w & 0xffff)) + bf2f((u16)(u.w >> 16));
    }
    s += __shfl_xor(s, 1); s += __shfl_xor(s, 2);
    if (seg == 0) vmean_lds[d] = s * (1.f / 256.f);
  }
  float lsum[2][4]; f32x4 cacc[2][8];
#pragma unroll
  for (int g = 0; g < 2; ++g)
#pragma unroll
    for (int rg = 0; rg < 4; ++rg) lsum[g][rg] = 0.f;
#pragma unroll
  for (int g = 0; g < 2; ++g)
#pragma unroll
    for (int ct = 0; ct < 8; ++ct) cacc[g][ct] = f32x4{0.f, 0.f, 0.f, 0.f};
  __syncthreads();  // barrier 3: vmean ready; no more block syncs

  // ---- attention: fixed-max softmax, 32 rows/wave ----
  const int nkv = (wv >> 1) + 1;
  for (int kv = 0; kv < nkv; ++kv) {
    const int s0 = kv * 64;
    f32x4 sacc[2][4];
#pragma unroll
    for (int g = 0; g < 2; ++g)
#pragma unroll
      for (int ct = 0; ct < 4; ++ct) sacc[g][ct] = f32x4{0.f, 0.f, 0.f, 0.f};
#pragma unroll
    for (int ct = 0; ct < 4; ++ct)
#pragma unroll
      for (int ks = 0; ks < 4; ++ks) {
        bf16x8 bfr = *(const bf16x8*)&KX[s0 + ct * 16 + l15][ks * 32 + l4 * 8];
#pragma unroll
        for (int g = 0; g < 2; ++g) sacc[g][ct] = MFMA16(qa[g][ks], bfr, sacc[g][ct]);
      }
    int km[4];
#pragma unroll
    for (int ct = 0; ct < 4; ++ct) km[ct] = mrow[s0 + ct * 16 + l15];
    float p[2][4][4];
#pragma unroll
    for (int g = 0; g < 2; ++g)
#pragma unroll
      for (int ct = 0; ct < 4; ++ct) {
        const int ss = s0 + ct * 16 + l15;
#pragma unroll
        for (int rg = 0; rg < 4; ++rg) {
          float sv = sacc[g][ct][rg] + rel_lds[ttg[g][rg] - ss + 255];
          bool msk = (ss > ttg[g][rg]) | (km[ct] == 0) | (qm[g][rg] == 0);
          sv = msk ? -1.0e9f : sv;
          float pv = __expf(sv);  // masked -> exactly 0
          p[g][ct][rg] = pv;
          lsum[g][rg] += pv;
        }
      }
#pragma unroll
    for (int c = 0; c < 2; ++c) {
#pragma unroll
      for (int g = 0; g < 2; ++g)
#pragma unroll
        for (int c2 = 0; c2 < 2; ++c2)
#pragma unroll
          for (int rg = 0; rg < 4; ++rg)
            P_lds[wv][g * 16 + 4 * l4 + rg][c2 * 16 + l15] = f2bf(p[g][2 * c + c2][rg]);
      bf16x8 pa[2];
#pragma unroll
      for (int g = 0; g < 2; ++g)
        pa[g] = *(const bf16x8*)&P_lds[wv][g * 16 + l15][l4 * 8];
#pragma unroll
      for (int ct = 0; ct < 8; ++ct) {
        bf16x8 vb = *(const bf16x8*)&V_lds[ct * 16 + l15][s0 + c * 32 + l4 * 8];
#pragma unroll
        for (int g = 0; g < 2; ++g) cacc[g][ct] = MFMA16(pa[g], vb, cacc[g][ct]);
      }
    }
  }
  float li[2][4];
#pragma unroll
  for (int g = 0; g < 2; ++g)
#pragma unroll
    for (int rg = 0; rg < 4; ++rg) {
      float rs = lsum[g][rg];
#pragma unroll
      for (int off = 1; off < 16; off <<= 1) rs += __shfl_xor(rs, off);
      li[g][rg] = rs;
    }
  // ---- ctx -> out-proj (ping-pong) -> residual+LN -> scatter ----
  bf16x8 ca[2][4];
#pragma unroll
  for (int q = 0; q < 4; ++q) {
#pragma unroll
    for (int g = 0; g < 2; ++g)
#pragma unroll
      for (int c2 = 0; c2 < 2; ++c2) {
        int ct = 2 * q + c2;
        float vm = vmean_lds[ct * 16 + l15];
#pragma unroll
        for (int rg = 0; rg < 4; ++rg) {
          float cval = cacc[g][ct][rg] / li[g][rg];
          cval = (qm[g][rg] == 0) ? vm : cval;
          P_lds[wv][g * 16 + 4 * l4 + rg][c2 * 16 + l15] = f2bf(cval);
        }
      }
#pragma unroll
    for (int g = 0; g < 2; ++g)
      ca[g][q] = *(const bf16x8*)&P_lds[wv][g * 16 + l15][l4 * 8];
  }
  f32x4 oacc[2][8];
#define OACC(CT)                                                           \
  do {                                                                     \
    oacc[0][CT] = t0; oacc[1][CT] = t1;                                    \
  } while (0)
#define MF8C(buf)                                                          \
  do {                                                                     \
    t0 = f32x4{0.f, 0.f, 0.f, 0.f}; t1 = f32x4{0.f, 0.f, 0.f, 0.f};       \
    _Pragma("unroll") for (int ks = 0; ks < 4; ++ks) {                     \
      t0 = MFMA16(ca[0][ks], buf[ks], t0);                                 \
      t1 = MFMA16(ca[1][ks], buf[ks], t1);                                 \
    }                                                                      \
  } while (0)
  LOADW4(bA, 384 + 0);
  LOADW4(bB, 384 + 16);
  MF8C(bA); LOADW4(bA, 384 + 2 * 16); OACC(0);
  MF8C(bB); LOADW4(bB, 384 + 3 * 16); OACC(1);
  MF8C(bA); LOADW4(bA, 384 + 4 * 16); OACC(2);
  MF8C(bB); LOADW4(bB, 384 + 5 * 16); OACC(3);
  MF8C(bA); LOADW4(bA, 384 + 6 * 16); OACC(4);
  MF8C(bB); LOADW4(bB, 384 + 7 * 16); OACC(5);
  MF8C(bA);                           OACC(6);
  MF8C(bB);                           OACC(7);

  float bpv[8], gv[8], bt[8];
#pragma unroll
  for (int ct = 0; ct < 8; ++ct) {
    int d = ct * 16 + l15;
    bpv[ct] = bp[d]; gv[ct] = ln_g[d]; bt[ct] = ln_b[d];
  }
#pragma unroll
  for (int g = 0; g < 2; ++g)
#pragma unroll
    for (int rg = 0; rg < 4; ++rg) {
      const int tg = ttg[g][rg];
      float yv[8], sum = 0.f, sq = 0.f;
#pragma unroll
      for (int ct = 0; ct < 8; ++ct) {
        uint32_t pr = xres[g][rg][ct >> 1];
        u16 xh = (ct & 1) ? (u16)(pr >> 16) : (u16)(pr & 0xffff);
        float v = oacc[g][ct][rg] + bpv[ct] + bf2f(xh);
        yv[ct] = v; sum += v; sq += v * v;
      }
#pragma unroll
      for (int off = 1; off < 16; off <<= 1) { sum += __shfl_xor(sum, off); sq += __shfl_xor(sq, off); }
      float mean = sum * (1.f / 128.f);
      float var = sq * (1.f / 128.f) - mean * mean;
      float rstd = rsqrtf(var + 1e-5f);
      float* orow = out + (((size_t)(bb * 256 + tg)) * 100 + rr) * 128;
#pragma unroll
      for (int ct = 0; ct < 8; ++ct)
        orow[ct * 16 + l15] = (yv[ct] - mean) * rstd * gv[ct] + bt[ct];
    }
#undef LOADW4
#undef MF8
#undef MF8C
#undef QSTORE
#undef QSTEP
#undef OACC
}

extern "C" void kernel_launch(void* const* d_in, const int* in_sizes, int n_in,
                              void* d_out, int out_size, void* d_ws, size_t ws_size,
                              hipStream_t stream) {
  const float* x    = (const float*)d_in[0];
  const int*   mask = (const int*)d_in[1];
  const float* Wq   = (const float*)d_in[2];
  const float* bq   = (const float*)d_in[3];
  const float* Wk   = (const float*)d_in[4];
  const float* bk   = (const float*)d_in[5];
  const float* Wv   = (const float*)d_in[6];
  const float* bv   = (const float*)d_in[7];
  const float* Wp   = (const float*)d_in[8];
  const float* bp   = (const float*)d_in[9];
  const float* ln_g = (const float*)d_in[10];
  const float* ln_b = (const float*)d_in[11];
  const float* rel  = (const float*)d_in[12];
  float* out = (float*)d_out;
  u16* Wt = (u16*)d_ws;  // [4][128][128] bf16 transposed — only workspace use

  hipLaunchKernelGGL(prep_weights_kernel, dim3(4, 64), dim3(256), 0, stream, Wq, Wk, Wv, Wp, Wt);
  hipLaunchKernelGGL(fused13_kernel, dim3(400), dim3(512), 0, stream,
                     Wt, x, mask, rel, bq, bk, bv, bp, ln_g, ln_b, out);
}